// Round 10
// baseline (848.609 us; speedup 1.0000x reference)
//
#include <hip/hip_runtime.h>
#include <math.h>

#define N_NODES 50000
#define N_EDGES 400000
#define IN_F 128
#define HC 176
#define NGRAPH 64

typedef _Float16 half8 __attribute__((ext_vector_type(8)));
typedef float floatx4 __attribute__((ext_vector_type(4)));

// =====================================================================
// Packed split-fp16 weights in MFMA B-fragment order.
// For each matrix: [kc][ct][s(hi/lo)][lane][j]  (halves)
//   value = W[kc*32 + (lane>>4)*8 + j][ct*16 + (lane&15)]  (0 if k >= K)
// Mat order: pre(nkc=4) | 4 layers x {Wl,Wr,Wres}(nkc=6) | c5Wl,c5Wr(nkc=6)
// =====================================================================
#define PREH 45056   // 4*11*2*512 halves
#define MATH 67584   // 6*11*2*512 halves
#define TOT_PAIRS 495616  // 22528 + 14*33792
#define KCBYTES 22528     // bytes per kc chunk (11*2*512*2)
#define GX8 49            // row-tile groups of 8 (49*8=392 >= 391 tiles)

__global__ void prep_kernel(const float* __restrict__ Wpre,
                            const float* __restrict__ cWl, const float* __restrict__ cWr,
                            const float* __restrict__ cWres,
                            const float* __restrict__ c5Wl, const float* __restrict__ c5Wr,
                            _Float16* __restrict__ wp) {
  int gid = blockIdx.x * 256 + threadIdx.x;
  if (gid >= TOT_PAIRS) return;
  int mat, idx;
  if (gid < 22528) { mat = 0; idx = gid; }
  else { int g = gid - 22528; mat = 1 + g / 33792; idx = g % 33792; }
  int kc = idx / 5632;
  int rem = idx - kc * 5632;
  int ct = rem / 512;
  int li = rem - ct * 512;
  int lane = li >> 3, j = li & 7;
  int k = kc * 32 + ((lane >> 4) << 3) + j;
  int col = ct * 16 + (lane & 15);
  const float* src; int Ksrc; size_t base;
  if (mat == 0) { src = Wpre; Ksrc = 128; base = 0; }
  else if (mat <= 12) {
    int lm = mat - 1; int layer = lm / 3; int sub = lm - layer * 3;
    const float* s = (sub == 0) ? cWl : (sub == 1) ? cWr : cWres;
    src = s + (size_t)layer * HC * HC; Ksrc = HC;
    base = PREH + (size_t)lm * MATH;
  } else {
    src = (mat == 13) ? c5Wl : c5Wr; Ksrc = HC;
    base = PREH + (size_t)12 * MATH + (size_t)(mat - 13) * MATH;
  }
  float v = (k < Ksrc) ? src[(size_t)k * HC + col] : 0.0f;
  _Float16 h = (_Float16)v;
  _Float16 l = (_Float16)(v - (float)h);
  size_t o = base + (size_t)(kc * 11 + ct) * 1024 + li;
  wp[o] = h;
  wp[o + 512] = l;
}

// =====================================================================
// Split-fp16 MFMA GEMM with block-level LDS staging of B (R7 structure)
// + XCD-aware block swizzle (R8): blocks sharing the same A row-tile but
// different mat have blockIdx.x differing by 8 -> same XCD.
// grid.x = GX8 * nmat * 8.
// =====================================================================
__global__ __launch_bounds__(256, 2) void gemm_mfma(
    const float* __restrict__ A, int M, int K, int nkc, int nmat,
    const _Float16* __restrict__ Wp, int matStride,
    const float* __restrict__ scsh, const int* __restrict__ batch,
    const float* __restrict__ bias0, const float* __restrict__ bias1,
    const float* __restrict__ bias2,
    float* __restrict__ out0, float* __restrict__ out1, float* __restrict__ out2) {
  __shared__ __align__(16) char smem[2 * KCBYTES];
  const int b = blockIdx.x;
  const int grp = b >> 3, sub = b & 7;
  const int mat = grp % nmat;
  const int tile = ((grp / nmat) << 3) | sub;
  if (tile * 128 >= M) return;
  const _Float16* W = Wp + (size_t)mat * matStride;
  float* outp = (mat == 0) ? out0 : (mat == 1) ? out1 : out2;
  const float* bias = (mat == 0) ? bias0 : (mat == 1) ? bias1 : bias2;
  const int tid = threadIdx.x;
  const int lane = tid & 63;
  const int wv = tid >> 6;
  const int m16 = lane & 15, quad = lane >> 4;
  const int kb = quad << 3;
  const int rowBase = tile * 128 + wv * 32;
  const int rA0 = min(rowBase + m16, M - 1);
  const int rA1 = min(rowBase + 16 + m16, M - 1);
  const float* ap0 = A + (size_t)rA0 * K + kb;
  const float* ap1 = A + (size_t)rA1 * K + kb;
  const float* sc0 = nullptr; const float* sh0 = nullptr;
  const float* sc1 = nullptr; const float* sh1 = nullptr;
  if (scsh) {
    int g0 = batch[rA0], g1 = batch[rA1];
    sc0 = scsh + (size_t)g0 * HC + kb;
    sh0 = scsh + (size_t)(NGRAPH + g0) * HC + kb;
    sc1 = scsh + (size_t)g1 * HC + kb;
    sh1 = scsh + (size_t)(NGRAPH + g1) * HC + kb;
  }

  auto stage = [&](int kc, int buf) {
    const char* src = (const char*)W + (size_t)kc * KCBYTES;
    char* dst = smem + buf * KCBYTES;
#pragma unroll
    for (int i = 0; i < 6; i++) {
      int idx = wv * 6 + i;
      if (idx < 22) {
        __builtin_amdgcn_global_load_lds(
            (const __attribute__((address_space(1))) unsigned int*)(src + idx * 1024 + lane * 16),
            (__attribute__((address_space(3))) unsigned int*)(dst + idx * 1024),
            16, 0, 0);
      }
    }
  };

  floatx4 acc0[11], acc1[11];
#pragma unroll
  for (int ct = 0; ct < 11; ct++)
#pragma unroll
    for (int r = 0; r < 4; r++) { acc0[ct][r] = 0.0f; acc1[ct][r] = 0.0f; }

  stage(0, 0);

  for (int kc = 0; kc < nkc; kc++) {
    const int buf = kc & 1;
    __syncthreads();
    if (kc + 1 < nkc) stage(kc + 1, 1 - buf);

    const int koff = kc << 5;
    float va0[8], va1[8];
    if (koff + kb + 8 <= K) {
      float4 u0 = *(const float4*)(ap0 + koff);
      float4 u1 = *(const float4*)(ap0 + koff + 4);
      float4 w0 = *(const float4*)(ap1 + koff);
      float4 w1 = *(const float4*)(ap1 + koff + 4);
      va0[0] = u0.x; va0[1] = u0.y; va0[2] = u0.z; va0[3] = u0.w;
      va0[4] = u1.x; va0[5] = u1.y; va0[6] = u1.z; va0[7] = u1.w;
      va1[0] = w0.x; va1[1] = w0.y; va1[2] = w0.z; va1[3] = w0.w;
      va1[4] = w1.x; va1[5] = w1.y; va1[6] = w1.z; va1[7] = w1.w;
      if (scsh) {
        float s0[8], h0[8], s1[8], h1[8];
        float4 t;
        t = *(const float4*)(sc0 + koff);     s0[0]=t.x; s0[1]=t.y; s0[2]=t.z; s0[3]=t.w;
        t = *(const float4*)(sc0 + koff + 4); s0[4]=t.x; s0[5]=t.y; s0[6]=t.z; s0[7]=t.w;
        t = *(const float4*)(sh0 + koff);     h0[0]=t.x; h0[1]=t.y; h0[2]=t.z; h0[3]=t.w;
        t = *(const float4*)(sh0 + koff + 4); h0[4]=t.x; h0[5]=t.y; h0[6]=t.z; h0[7]=t.w;
        t = *(const float4*)(sc1 + koff);     s1[0]=t.x; s1[1]=t.y; s1[2]=t.z; s1[3]=t.w;
        t = *(const float4*)(sc1 + koff + 4); s1[4]=t.x; s1[5]=t.y; s1[6]=t.z; s1[7]=t.w;
        t = *(const float4*)(sh1 + koff);     h1[0]=t.x; h1[1]=t.y; h1[2]=t.z; h1[3]=t.w;
        t = *(const float4*)(sh1 + koff + 4); h1[4]=t.x; h1[5]=t.y; h1[6]=t.z; h1[7]=t.w;
#pragma unroll
        for (int j = 0; j < 8; j++) {
          va0[j] = fmaxf(fmaf(va0[j], s0[j], h0[j]), 0.0f);
          va1[j] = fmaxf(fmaf(va1[j], s1[j], h1[j]), 0.0f);
        }
      }
    } else {
#pragma unroll
      for (int j = 0; j < 8; j++) { va0[j] = 0.0f; va1[j] = 0.0f; }
    }
    half8 ah0, al0, ah1, al1;
#pragma unroll
    for (int j = 0; j < 8; j++) {
      _Float16 h = (_Float16)va0[j];
      ah0[j] = h; al0[j] = (_Float16)(va0[j] - (float)h);
      _Float16 g = (_Float16)va1[j];
      ah1[j] = g; al1[j] = (_Float16)(va1[j] - (float)g);
    }
    const char* bbase = smem + buf * KCBYTES + lane * 16;
#pragma unroll
    for (int ct = 0; ct < 11; ct++) {
      half8 bh = *(const half8*)(bbase + ct * 2048);
      half8 bl = *(const half8*)(bbase + ct * 2048 + 1024);
      acc0[ct] = __builtin_amdgcn_mfma_f32_16x16x32_f16(ah0, bh, acc0[ct], 0, 0, 0);
      acc1[ct] = __builtin_amdgcn_mfma_f32_16x16x32_f16(ah1, bh, acc1[ct], 0, 0, 0);
      acc0[ct] = __builtin_amdgcn_mfma_f32_16x16x32_f16(al0, bh, acc0[ct], 0, 0, 0);
      acc1[ct] = __builtin_amdgcn_mfma_f32_16x16x32_f16(al1, bh, acc1[ct], 0, 0, 0);
      acc0[ct] = __builtin_amdgcn_mfma_f32_16x16x32_f16(ah0, bl, acc0[ct], 0, 0, 0);
      acc1[ct] = __builtin_amdgcn_mfma_f32_16x16x32_f16(ah1, bl, acc1[ct], 0, 0, 0);
    }
  }

  float bv[11];
#pragma unroll
  for (int ct = 0; ct < 11; ct++) bv[ct] = bias ? bias[ct * 16 + m16] : 0.0f;
#pragma unroll
  for (int r = 0; r < 4; r++) {
    int row0 = rowBase + (quad << 2) + r;
    if (row0 < M) {
      float* op = outp + (size_t)row0 * HC + m16;
#pragma unroll
      for (int ct = 0; ct < 11; ct++) op[ct * 16] = acc0[ct][r] + bv[ct];
    }
    int row1 = row0 + 16;
    if (row1 < M) {
      float* op = outp + (size_t)row1 * HC + m16;
#pragma unroll
      for (int ct = 0; ct < 11; ct++) op[ct * 16] = acc1[ct][r] + bv[ct];
    }
  }
}

// =====================================================================
// GraphNorm: stats (sum, sumsq per graph/feature) + finalize -> scale/shift
// (apply is fused into the consumers; 5 separate stat buffers, one memset)
// =====================================================================
__global__ void gn_stats_kernel(const float* __restrict__ h, const int* __restrict__ batch,
                                float* __restrict__ stats) {
  int f = threadIdx.x;
  if (f >= HC) return;
  int n0 = blockIdx.x * 64;
  int n1 = min(n0 + 64, N_NODES);
  float s = 0.0f, ss = 0.0f;
  int gcur = batch[n0];
  for (int n = n0; n < n1; n++) {
    int g = batch[n];
    if (g != gcur) {
      atomicAdd(&stats[gcur * HC + f], s);
      atomicAdd(&stats[NGRAPH * HC + gcur * HC + f], ss);
      s = 0.0f; ss = 0.0f; gcur = g;
    }
    float v = h[(size_t)n * HC + f];
    s += v;
    ss += v * v;
  }
  atomicAdd(&stats[gcur * HC + f], s);
  atomicAdd(&stats[NGRAPH * HC + gcur * HC + f], ss);
}

__global__ void gn_finalize_kernel(const float* __restrict__ stats, const int* __restrict__ cntInt,
                                   const float* __restrict__ gnw, const float* __restrict__ gnb,
                                   const float* __restrict__ gnms, int row,
                                   float* __restrict__ scsh) {
  int i = blockIdx.x * 256 + threadIdx.x;
  if (i >= NGRAPH * HC) return;
  int g = i / HC, f = i - g * HC;
  float c = fmaxf((float)cntInt[g], 1.0f);
  float m = stats[i] / c;
  float sq = stats[NGRAPH * HC + i] / c;
  float ms = gnms[row * HC + f];
  float var = sq - m * m * ms * (2.0f - ms);
  float w = gnw[row * HC + f], b = gnb[row * HC + f];
  float scale = w / sqrtf(var + 1e-5f);
  float shift = b - scale * ms * m;
  scsh[i] = scale;
  scsh[NGRAPH * HC + i] = shift;
}

// =====================================================================
// Per-graph node counts via binary search over the SORTED batch array.
// =====================================================================
__global__ void cnt_bsearch_kernel(const int* __restrict__ batch, int* __restrict__ cntInt) {
  int g = threadIdx.x;
  if (g >= NGRAPH) return;
  auto lb = [&](int v) {
    int lo = 0, hi = N_NODES;
    while (lo < hi) {
      int mid = (lo + hi) >> 1;
      if (batch[mid] < v) lo = mid + 1; else hi = mid;
    }
    return lo;
  };
  int a = lb(g), b = lb(g + 1);
  cntInt[g] = b - a;
}

// =====================================================================
// CSR build by destination
// =====================================================================
__global__ void deg_hist_kernel(const int* __restrict__ dstE, int* __restrict__ deg) {
  int e = blockIdx.x * 256 + threadIdx.x;
  if (e < N_EDGES) atomicAdd(&deg[dstE[e]], 1);
}

__global__ void scan1_kernel(const int* __restrict__ deg, int* __restrict__ bsum) {
  __shared__ int sd[256];
  int i = blockIdx.x * 256 + threadIdx.x;
  sd[threadIdx.x] = (i < N_NODES) ? deg[i] : 0;
  __syncthreads();
  for (int s = 128; s > 0; s >>= 1) {
    if (threadIdx.x < s) sd[threadIdx.x] += sd[threadIdx.x + s];
    __syncthreads();
  }
  if (threadIdx.x == 0) bsum[blockIdx.x] = sd[0];
}

__global__ void scan2_kernel(int* __restrict__ bsum, int nb) {
  __shared__ int sd[256];
  int t = threadIdx.x;
  int v0 = (t < nb) ? bsum[t] : 0;
  sd[t] = v0;
  __syncthreads();
  for (int s = 1; s < 256; s <<= 1) {
    int v = (t >= s) ? sd[t - s] : 0;
    __syncthreads();
    sd[t] += v;
    __syncthreads();
  }
  if (t < nb) bsum[t] = sd[t] - v0;  // exclusive
}

__global__ void scan3_kernel(const int* __restrict__ deg, const int* __restrict__ bsum,
                             int* __restrict__ rowptr) {
  __shared__ int sd[256];
  int i = blockIdx.x * 256 + threadIdx.x;
  int t = threadIdx.x;
  int d = (i < N_NODES) ? deg[i] : 0;
  sd[t] = d;
  __syncthreads();
  for (int s = 1; s < 256; s <<= 1) {
    int v = (t >= s) ? sd[t - s] : 0;
    __syncthreads();
    sd[t] += v;
    __syncthreads();
  }
  if (i < N_NODES) rowptr[i] = bsum[blockIdx.x] + sd[t] - d;
  if (i == 0) rowptr[N_NODES] = N_EDGES;
}

__global__ void scatter_kernel(const int* __restrict__ srcE, const int* __restrict__ dstE,
                               const int* __restrict__ rowptr, int* __restrict__ fill,
                               int* __restrict__ colA) {
  int e = blockIdx.x * 256 + threadIdx.x;
  if (e < N_EDGES) {
    int d = dstE[e];
    int pos = rowptr[d] + atomicAdd(&fill[d], 1);
    colA[pos] = srcE[e];
  }
}

// =====================================================================
// GATv2 attention (R7 body, wg=64: 1 wave = 1 node). Tiny logits ->
// direct exp, commutative accumulation, 2-wide pipelined edge loop.
// One-wave workgroups free their CU slot as soon as their node finishes
// (degree variance no longer holds 4-wave groups hostage) -> higher
// average occupancy -> more gathers in flight.
// Lane L (<44) owns features 4L..4L+3 (one head per lane group of 4).
// =====================================================================
#define AEDGE(V, D, ACC)                                                      \
  do {                                                                        \
    float e0 = (V).x + xrv.x; e0 = fmaxf(e0, 0.2f * e0);                      \
    float e1 = (V).y + xrv.y; e1 = fmaxf(e1, 0.2f * e1);                      \
    float e2 = (V).z + xrv.z; e2 = fmaxf(e2, 0.2f * e2);                      \
    float e3 = (V).w + xrv.w; e3 = fmaxf(e3, 0.2f * e3);                      \
    float p = fmaf(e3, av.w, fmaf(e2, av.z, fmaf(e1, av.y, e0 * av.x)));      \
    p += __shfl_xor(p, 1);                                                    \
    p += __shfl_xor(p, 2);                                                    \
    float pp = __expf(p);                                                     \
    (D) += pp;                                                                \
    (ACC).x = fmaf(pp, (V).x, (ACC).x);                                       \
    (ACC).y = fmaf(pp, (V).y, (ACC).y);                                       \
    (ACC).z = fmaf(pp, (V).z, (ACC).z);                                       \
    (ACC).w = fmaf(pp, (V).w, (ACC).w);                                       \
  } while (0)

__global__ __launch_bounds__(64) void attn_concat_kernel(
    const float* __restrict__ xl, const float* __restrict__ xr,
    const float* __restrict__ att, const int* __restrict__ rowptr,
    const int* __restrict__ colA, float* __restrict__ out) {
  int node = blockIdx.x;
  int lane = threadIdx.x;
  if (lane >= 44) return;
  const float4 av = *(const float4*)(att + lane * 4);
  size_t base = (size_t)node * HC + lane * 4;
  const float4 xrv = *(const float4*)(xr + base);
  int start = rowptr[node], end = rowptr[node + 1];
  float d = 0.0f, dB = 0.0f;
  float4 acc = make_float4(0.f, 0.f, 0.f, 0.f);
  float4 accB = make_float4(0.f, 0.f, 0.f, 0.f);
  float4 p1, p2;
  if (start < end)     p1 = *(const float4*)(xl + (size_t)colA[start] * HC + lane * 4);
  if (start + 1 < end) p2 = *(const float4*)(xl + (size_t)colA[start + 1] * HC + lane * 4);
  {
    float4 sv = *(const float4*)(xl + base);  // self-loop
    AEDGE(sv, d, acc);
  }
  int j = start;
  for (; j + 3 < end; j += 2) {
    float4 n1 = *(const float4*)(xl + (size_t)colA[j + 2] * HC + lane * 4);
    float4 n2 = *(const float4*)(xl + (size_t)colA[j + 3] * HC + lane * 4);
    AEDGE(p1, d, acc);
    AEDGE(p2, dB, accB);
    p1 = n1; p2 = n2;
  }
  if (j < end)     AEDGE(p1, d, acc);
  if (j + 1 < end) AEDGE(p2, dB, accB);
  if (j + 2 < end) {
    float4 n1 = *(const float4*)(xl + (size_t)colA[j + 2] * HC + lane * 4);
    AEDGE(n1, d, acc);
  }
  d += dB;
  acc.x += accB.x; acc.y += accB.y; acc.z += accB.z; acc.w += accB.w;
  float rd = 1.0f / (d + 1e-16f);
  float4 o = *(const float4*)(out + base);  // residual+bias already there
  o.x = fmaf(acc.x, rd, o.x);
  o.y = fmaf(acc.y, rd, o.y);
  o.z = fmaf(acc.z, rd, o.z);
  o.w = fmaf(acc.w, rd, o.w);
  *(float4*)(out + base) = o;
}

__global__ __launch_bounds__(64) void attn_mean_kernel(
    const float* __restrict__ xl, const float* __restrict__ xr,
    const float* __restrict__ att, const int* __restrict__ rowptr,
    const int* __restrict__ colA, const float* __restrict__ res16,
    float* __restrict__ out16) {
  int node = blockIdx.x;
  int lane = threadIdx.x;
  int L = (lane < 44) ? lane : 0;  // lanes 44..63 ride along (zeroed later)
  const float4 av = *(const float4*)(att + L * 4);
  size_t base = (size_t)node * HC + L * 4;
  const float4 xrv = *(const float4*)(xr + base);
  int start = rowptr[node], end = rowptr[node + 1];
  float d = 0.0f, dB = 0.0f;
  float4 acc = make_float4(0.f, 0.f, 0.f, 0.f);
  float4 accB = make_float4(0.f, 0.f, 0.f, 0.f);
  float4 p1, p2;
  if (start < end)     p1 = *(const float4*)(xl + (size_t)colA[start] * HC + L * 4);
  if (start + 1 < end) p2 = *(const float4*)(xl + (size_t)colA[start + 1] * HC + L * 4);
  {
    float4 sv = *(const float4*)(xl + base);
    AEDGE(sv, d, acc);
  }
  int j = start;
  for (; j + 3 < end; j += 2) {
    float4 n1 = *(const float4*)(xl + (size_t)colA[j + 2] * HC + L * 4);
    float4 n2 = *(const float4*)(xl + (size_t)colA[j + 3] * HC + L * 4);
    AEDGE(p1, d, acc);
    AEDGE(p2, dB, accB);
    p1 = n1; p2 = n2;
  }
  if (j < end)     AEDGE(p1, d, acc);
  if (j + 1 < end) AEDGE(p2, dB, accB);
  if (j + 2 < end) {
    float4 n1 = *(const float4*)(xl + (size_t)colA[j + 2] * HC + L * 4);
    AEDGE(n1, d, acc);
  }
  d += dB;
  acc.x += accB.x; acc.y += accB.y; acc.z += accB.z; acc.w += accB.w;
  float rd = 1.0f / (d + 1e-16f);
  float4 o;
  o.x = (lane < 44) ? acc.x * rd : 0.0f;
  o.y = (lane < 44) ? acc.y * rd : 0.0f;
  o.z = (lane < 44) ? acc.z * rd : 0.0f;
  o.w = (lane < 44) ? acc.w * rd : 0.0f;
#pragma unroll
  for (int w = 4; w <= 32; w <<= 1) {
    o.x += __shfl_xor(o.x, w);
    o.y += __shfl_xor(o.y, w);
    o.z += __shfl_xor(o.z, w);
    o.w += __shfl_xor(o.w, w);
  }
  if (lane < 4) {
    const float* rp = res16 + (size_t)node * 16 + lane * 4;
    float4 r = *(const float4*)rp;
    float4 ov;
    ov.x = fmaxf(fmaf(o.x, 1.0f / 11.0f, r.x), 0.0f);
    ov.y = fmaxf(fmaf(o.y, 1.0f / 11.0f, r.y), 0.0f);
    ov.z = fmaxf(fmaf(o.z, 1.0f / 11.0f, r.z), 0.0f);
    ov.w = fmaxf(fmaf(o.w, 1.0f / 11.0f, r.w), 0.0f);
    *(float4*)(out16 + (size_t)node * 16 + lane * 4) = ov;
  }
}

// =====================================================================
// res16 = normApply(h) @ c5_Wres(176x16) + c5_b   (norm+relu fused in load)
// =====================================================================
__global__ __launch_bounds__(256) void res16_kernel(const float* __restrict__ h,
                                                    const float* __restrict__ scsh,
                                                    const int* __restrict__ batch,
                                                    const float* __restrict__ Wres,
                                                    const float* __restrict__ b16,
                                                    float* __restrict__ res16) {
  __shared__ float Ws[176 * 16];
  __shared__ float hs[16 * 176];
  int t = threadIdx.x;
  for (int i = t; i < 176 * 16; i += 256) Ws[i] = Wres[i];
  int n0 = blockIdx.x * 16;
  for (int i = t; i < 16 * 176; i += 256) {
    int row = i / 176, k = i - row * 176;
    int g = batch[n0 + row];
    float v = h[(size_t)n0 * HC + i];
    hs[i] = fmaxf(fmaf(v, scsh[g * HC + k], scsh[(NGRAPH + g) * HC + k]), 0.0f);
  }
  __syncthreads();
  int tx = t & 15, ty = t >> 4;
  float acc = b16[tx];
  for (int k = 0; k < HC; k++) acc = fmaf(hs[ty * HC + k], Ws[k * 16 + tx], acc);
  res16[(size_t)(n0 + ty) * 16 + tx] = acc;
}

// =====================================================================
// Head MLP
// =====================================================================
__global__ __launch_bounds__(256) void head_kernel(
    const float* __restrict__ in16, const float* __restrict__ Wo1,
    const float* __restrict__ bo1, const float* __restrict__ Wo2,
    const float* __restrict__ bo2, const float* __restrict__ Wc,
    const float* __restrict__ bc, float* __restrict__ outp) {
  __shared__ float w1[256], w2[512], wcS[320], b1[16], b2[32], bcS[10];
  int t = threadIdx.x;
  for (int i = t; i < 256; i += 256) w1[i] = Wo1[i];
  for (int i = t; i < 512; i += 256) w2[i] = Wo2[i];
  for (int i = t; i < 320; i += 256) wcS[i] = Wc[i];
  if (t < 16) b1[t] = bo1[t];
  if (t < 32) b2[t] = bo2[t];
  if (t < 10) bcS[t] = bc[t];
  __syncthreads();
  int n = blockIdx.x * 256 + t;
  if (n >= N_NODES) return;
  float x[16];
#pragma unroll
  for (int i = 0; i < 16; i++) x[i] = in16[(size_t)n * 16 + i];
  float o1[16];
#pragma unroll
  for (int j = 0; j < 16; j++) {
    float a = b1[j];
#pragma unroll
    for (int k = 0; k < 16; k++) a = fmaf(x[k], w1[k * 16 + j], a);
    o1[j] = fmaxf(a, 0.0f);
  }
  float o2[32];
#pragma unroll
  for (int j = 0; j < 32; j++) {
    float a = b2[j];
#pragma unroll
    for (int k = 0; k < 16; k++) a = fmaf(o1[k], w2[k * 32 + j], a);
    o2[j] = fmaxf(a, 0.0f);
  }
#pragma unroll
  for (int j = 0; j < 10; j++) {
    float a = bcS[j];
#pragma unroll
    for (int k = 0; k < 32; k++) a = fmaf(o2[k], wcS[k * 10 + j], a);
    outp[(size_t)n * 10 + j] = a;
  }
}

// =====================================================================
extern "C" void kernel_launch(void* const* d_in, const int* in_sizes, int n_in,
                              void* d_out, int out_size, void* d_ws, size_t ws_size,
                              hipStream_t stream) {
  (void)in_sizes; (void)n_in; (void)out_size; (void)ws_size;
  const float* x     = (const float*)d_in[0];
  const int*   ei    = (const int*)d_in[1];
  const int*   srcE  = ei;
  const int*   dstE  = ei + N_EDGES;
  const int*   batch = (const int*)d_in[2];
  const float* W_pre = (const float*)d_in[3];
  const float* b_pre = (const float*)d_in[4];
  const float* gn_w  = (const float*)d_in[5];
  const float* gn_b  = (const float*)d_in[6];
  const float* gn_ms = (const float*)d_in[7];
  const float* cWl   = (const float*)d_in[8];
  const float* cWr   = (const float*)d_in[9];
  const float* cAtt  = (const float*)d_in[10];
  const float* cB    = (const float*)d_in[11];
  const float* cWres = (const float*)d_in[12];
  const float* c5Wl  = (const float*)d_in[13];
  const float* c5Wr  = (const float*)d_in[14];
  const float* c5Att = (const float*)d_in[15];
  const float* c5b   = (const float*)d_in[16];
  const float* c5Wres= (const float*)d_in[17];
  const float* Wo1   = (const float*)d_in[18];
  const float* bo1   = (const float*)d_in[19];
  const float* Wo2   = (const float*)d_in[20];
  const float* bo2   = (const float*)d_in[21];
  const float* Wc    = (const float*)d_in[22];
  const float* bc    = (const float*)d_in[23];

  const size_t FB = (size_t)N_NODES * HC;
  const size_t STB = (size_t)2 * NGRAPH * HC;  // one stats buffer (22528 floats)
  float* ws    = (float*)d_ws;
  float* buf0  = ws;
  float* buf1  = ws + FB;
  float* buf2  = ws + 2 * FB;
  float* buf3  = ws + 3 * FB;
  float* res16 = ws + 4 * FB;
  float* out16 = res16 + (size_t)N_NODES * 16;
  float* stats = out16 + (size_t)N_NODES * 16;         // 5 buffers
  float* scsh  = stats + 5 * STB;
  _Float16* wph = (_Float16*)(scsh + STB);             // 991232 halves
  int* ibase   = (int*)((char*)wph + (size_t)991232 * 2);
  int* cntInt  = ibase;
  int* deg     = ibase + 64;
  int* fill    = deg + N_NODES;
  int* rowptr  = fill + N_NODES;
  int* colA    = rowptr + N_NODES + 1;
  int* bsum    = colA + N_EDGES;

  const int NB = (N_NODES + 255) / 256;

  hipMemsetAsync(deg, 0, sizeof(int) * 2 * N_NODES, stream);
  hipMemsetAsync(stats, 0, sizeof(float) * 5 * STB, stream);  // all layers at once

  prep_kernel<<<(TOT_PAIRS + 255) / 256, 256, 0, stream>>>(W_pre, cWl, cWr, cWres, c5Wl, c5Wr, wph);
  cnt_bsearch_kernel<<<1, 64, 0, stream>>>(batch, cntInt);
  deg_hist_kernel<<<(N_EDGES + 255) / 256, 256, 0, stream>>>(dstE, deg);
  scan1_kernel<<<NB, 256, 0, stream>>>(deg, bsum);
  scan2_kernel<<<1, 256, 0, stream>>>(bsum, NB);
  scan3_kernel<<<NB, 256, 0, stream>>>(deg, bsum, rowptr);
  scatter_kernel<<<(N_EDGES + 255) / 256, 256, 0, stream>>>(srcE, dstE, rowptr, fill, colA);

  // pre: buf0 = x @ W_pre + b_pre  (raw, no norm on input)
  gemm_mfma<<<GX8 * 1 * 8, 256, 0, stream>>>(x, N_NODES, IN_F, 4, 1, wph, 0,
                                             nullptr, nullptr,
                                             b_pre, nullptr, nullptr,
                                             buf0, nullptr, nullptr);
  gn_stats_kernel<<<(N_NODES + 63) / 64, 256, 0, stream>>>(buf0, batch, stats);
  gn_finalize_kernel<<<(NGRAPH * HC + 255) / 256, 256, 0, stream>>>(stats, cntInt, gn_w, gn_b, gn_ms, 0, scsh);

  float* h = buf0;  // raw buffer; norm applied on the fly by consumers
  float* o = buf3;
  for (int i = 0; i < 4; i++) {
    const _Float16* Wcat_i = wph + PREH + (size_t)(3 * i) * MATH;
    gemm_mfma<<<GX8 * 3 * 8, 256, 0, stream>>>(h, N_NODES, HC, 6, 3, Wcat_i, MATH,
                                               scsh, batch,
                                               nullptr, nullptr, cB + i * HC,
                                               buf1, buf2, o);
    attn_concat_kernel<<<N_NODES, 64, 0, stream>>>(buf1, buf2, cAtt + i * HC, rowptr, colA, o);
    float* st = stats + (size_t)(i + 1) * STB;
    gn_stats_kernel<<<(N_NODES + 63) / 64, 256, 0, stream>>>(o, batch, st);
    gn_finalize_kernel<<<(NGRAPH * HC + 255) / 256, 256, 0, stream>>>(st, cntInt, gn_w, gn_b, gn_ms, i + 1, scsh);
    float* tmp = h; h = o; o = tmp;
  }

  // conv5 (input = raw h with scsh row 4 fused in consumers)
  const _Float16* Wc5 = wph + PREH + (size_t)12 * MATH;
  gemm_mfma<<<GX8 * 2 * 8, 256, 0, stream>>>(h, N_NODES, HC, 6, 2, Wc5, MATH,
                                             scsh, batch,
                                             nullptr, nullptr, nullptr,
                                             buf1, buf2, nullptr);
  res16_kernel<<<N_NODES / 16, 256, 0, stream>>>(h, scsh, batch, c5Wres, c5b, res16);
  attn_mean_kernel<<<N_NODES, 64, 0, stream>>>(buf1, buf2, c5Att, rowptr, colA, res16, out16);

  head_kernel<<<NB, 256, 0, stream>>>(out16, Wo1, bo1, Wo2, bo2, Wc, bc, (float*)d_out);
}

// Round 11
// 813.006 us; speedup vs baseline: 1.0438x; 1.0438x over previous
//
#include <hip/hip_runtime.h>
#include <math.h>

#define N_NODES 50000
#define N_EDGES 400000
#define IN_F 128
#define HC 176
#define NGRAPH 64

typedef _Float16 half8 __attribute__((ext_vector_type(8)));
typedef float floatx4 __attribute__((ext_vector_type(4)));

// =====================================================================
// Packed split-fp16 weights in MFMA B-fragment order.
// For each matrix: [kc][ct][s(hi/lo)][lane][j]  (halves)
//   value = W[kc*32 + (lane>>4)*8 + j][ct*16 + (lane&15)]  (0 if k >= K)
// Mat order: pre(nkc=4) | 4 layers x {Wl,Wr,Wres}(nkc=6) | c5Wl,c5Wr(nkc=6)
// =====================================================================
#define PREH 45056   // 4*11*2*512 halves
#define MATH 67584   // 6*11*2*512 halves
#define TOT_PAIRS 495616  // 22528 + 14*33792
#define KCBYTES 22528     // bytes per kc chunk (11*2*512*2)
#define GX8 49            // row-tile groups of 8 (49*8=392 >= 391 tiles)

__global__ void prep_kernel(const float* __restrict__ Wpre,
                            const float* __restrict__ cWl, const float* __restrict__ cWr,
                            const float* __restrict__ cWres,
                            const float* __restrict__ c5Wl, const float* __restrict__ c5Wr,
                            _Float16* __restrict__ wp) {
  int gid = blockIdx.x * 256 + threadIdx.x;
  if (gid >= TOT_PAIRS) return;
  int mat, idx;
  if (gid < 22528) { mat = 0; idx = gid; }
  else { int g = gid - 22528; mat = 1 + g / 33792; idx = g % 33792; }
  int kc = idx / 5632;
  int rem = idx - kc * 5632;
  int ct = rem / 512;
  int li = rem - ct * 512;
  int lane = li >> 3, j = li & 7;
  int k = kc * 32 + ((lane >> 4) << 3) + j;
  int col = ct * 16 + (lane & 15);
  const float* src; int Ksrc; size_t base;
  if (mat == 0) { src = Wpre; Ksrc = 128; base = 0; }
  else if (mat <= 12) {
    int lm = mat - 1; int layer = lm / 3; int sub = lm - layer * 3;
    const float* s = (sub == 0) ? cWl : (sub == 1) ? cWr : cWres;
    src = s + (size_t)layer * HC * HC; Ksrc = HC;
    base = PREH + (size_t)lm * MATH;
  } else {
    src = (mat == 13) ? c5Wl : c5Wr; Ksrc = HC;
    base = PREH + (size_t)12 * MATH + (size_t)(mat - 13) * MATH;
  }
  float v = (k < Ksrc) ? src[(size_t)k * HC + col] : 0.0f;
  _Float16 h = (_Float16)v;
  _Float16 l = (_Float16)(v - (float)h);
  size_t o = base + (size_t)(kc * 11 + ct) * 1024 + li;
  wp[o] = h;
  wp[o + 512] = l;
}

// =====================================================================
// Split-fp16 MFMA GEMM with block-level LDS staging of B (R7 structure)
// + XCD-aware block swizzle (R8): blocks sharing the same A row-tile but
// different mat have blockIdx.x differing by 8 -> same XCD.
// grid.x = GX8 * nmat * 8.
// =====================================================================
__global__ __launch_bounds__(256, 2) void gemm_mfma(
    const float* __restrict__ A, int M, int K, int nkc, int nmat,
    const _Float16* __restrict__ Wp, int matStride,
    const float* __restrict__ scsh, const int* __restrict__ batch,
    const float* __restrict__ bias0, const float* __restrict__ bias1,
    const float* __restrict__ bias2,
    float* __restrict__ out0, float* __restrict__ out1, float* __restrict__ out2) {
  __shared__ __align__(16) char smem[2 * KCBYTES];
  const int b = blockIdx.x;
  const int grp = b >> 3, sub = b & 7;
  const int mat = grp % nmat;
  const int tile = ((grp / nmat) << 3) | sub;
  if (tile * 128 >= M) return;
  const _Float16* W = Wp + (size_t)mat * matStride;
  float* outp = (mat == 0) ? out0 : (mat == 1) ? out1 : out2;
  const float* bias = (mat == 0) ? bias0 : (mat == 1) ? bias1 : bias2;
  const int tid = threadIdx.x;
  const int lane = tid & 63;
  const int wv = tid >> 6;
  const int m16 = lane & 15, quad = lane >> 4;
  const int kb = quad << 3;
  const int rowBase = tile * 128 + wv * 32;
  const int rA0 = min(rowBase + m16, M - 1);
  const int rA1 = min(rowBase + 16 + m16, M - 1);
  const float* ap0 = A + (size_t)rA0 * K + kb;
  const float* ap1 = A + (size_t)rA1 * K + kb;
  const float* sc0 = nullptr; const float* sh0 = nullptr;
  const float* sc1 = nullptr; const float* sh1 = nullptr;
  if (scsh) {
    int g0 = batch[rA0], g1 = batch[rA1];
    sc0 = scsh + (size_t)g0 * HC + kb;
    sh0 = scsh + (size_t)(NGRAPH + g0) * HC + kb;
    sc1 = scsh + (size_t)g1 * HC + kb;
    sh1 = scsh + (size_t)(NGRAPH + g1) * HC + kb;
  }

  auto stage = [&](int kc, int buf) {
    const char* src = (const char*)W + (size_t)kc * KCBYTES;
    char* dst = smem + buf * KCBYTES;
#pragma unroll
    for (int i = 0; i < 6; i++) {
      int idx = wv * 6 + i;
      if (idx < 22) {
        __builtin_amdgcn_global_load_lds(
            (const __attribute__((address_space(1))) unsigned int*)(src + idx * 1024 + lane * 16),
            (__attribute__((address_space(3))) unsigned int*)(dst + idx * 1024),
            16, 0, 0);
      }
    }
  };

  floatx4 acc0[11], acc1[11];
#pragma unroll
  for (int ct = 0; ct < 11; ct++)
#pragma unroll
    for (int r = 0; r < 4; r++) { acc0[ct][r] = 0.0f; acc1[ct][r] = 0.0f; }

  stage(0, 0);

  for (int kc = 0; kc < nkc; kc++) {
    const int buf = kc & 1;
    __syncthreads();
    if (kc + 1 < nkc) stage(kc + 1, 1 - buf);

    const int koff = kc << 5;
    float va0[8], va1[8];
    if (koff + kb + 8 <= K) {
      float4 u0 = *(const float4*)(ap0 + koff);
      float4 u1 = *(const float4*)(ap0 + koff + 4);
      float4 w0 = *(const float4*)(ap1 + koff);
      float4 w1 = *(const float4*)(ap1 + koff + 4);
      va0[0] = u0.x; va0[1] = u0.y; va0[2] = u0.z; va0[3] = u0.w;
      va0[4] = u1.x; va0[5] = u1.y; va0[6] = u1.z; va0[7] = u1.w;
      va1[0] = w0.x; va1[1] = w0.y; va1[2] = w0.z; va1[3] = w0.w;
      va1[4] = w1.x; va1[5] = w1.y; va1[6] = w1.z; va1[7] = w1.w;
      if (scsh) {
        float s0[8], h0[8], s1[8], h1[8];
        float4 t;
        t = *(const float4*)(sc0 + koff);     s0[0]=t.x; s0[1]=t.y; s0[2]=t.z; s0[3]=t.w;
        t = *(const float4*)(sc0 + koff + 4); s0[4]=t.x; s0[5]=t.y; s0[6]=t.z; s0[7]=t.w;
        t = *(const float4*)(sh0 + koff);     h0[0]=t.x; h0[1]=t.y; h0[2]=t.z; h0[3]=t.w;
        t = *(const float4*)(sh0 + koff + 4); h0[4]=t.x; h0[5]=t.y; h0[6]=t.z; h0[7]=t.w;
        t = *(const float4*)(sc1 + koff);     s1[0]=t.x; s1[1]=t.y; s1[2]=t.z; s1[3]=t.w;
        t = *(const float4*)(sc1 + koff + 4); s1[4]=t.x; s1[5]=t.y; s1[6]=t.z; s1[7]=t.w;
        t = *(const float4*)(sh1 + koff);     h1[0]=t.x; h1[1]=t.y; h1[2]=t.z; h1[3]=t.w;
        t = *(const float4*)(sh1 + koff + 4); h1[4]=t.x; h1[5]=t.y; h1[6]=t.z; h1[7]=t.w;
#pragma unroll
        for (int j = 0; j < 8; j++) {
          va0[j] = fmaxf(fmaf(va0[j], s0[j], h0[j]), 0.0f);
          va1[j] = fmaxf(fmaf(va1[j], s1[j], h1[j]), 0.0f);
        }
      }
    } else {
#pragma unroll
      for (int j = 0; j < 8; j++) { va0[j] = 0.0f; va1[j] = 0.0f; }
    }
    half8 ah0, al0, ah1, al1;
#pragma unroll
    for (int j = 0; j < 8; j++) {
      _Float16 h = (_Float16)va0[j];
      ah0[j] = h; al0[j] = (_Float16)(va0[j] - (float)h);
      _Float16 g = (_Float16)va1[j];
      ah1[j] = g; al1[j] = (_Float16)(va1[j] - (float)g);
    }
    const char* bbase = smem + buf * KCBYTES + lane * 16;
#pragma unroll
    for (int ct = 0; ct < 11; ct++) {
      half8 bh = *(const half8*)(bbase + ct * 2048);
      half8 bl = *(const half8*)(bbase + ct * 2048 + 1024);
      acc0[ct] = __builtin_amdgcn_mfma_f32_16x16x32_f16(ah0, bh, acc0[ct], 0, 0, 0);
      acc1[ct] = __builtin_amdgcn_mfma_f32_16x16x32_f16(ah1, bh, acc1[ct], 0, 0, 0);
      acc0[ct] = __builtin_amdgcn_mfma_f32_16x16x32_f16(al0, bh, acc0[ct], 0, 0, 0);
      acc1[ct] = __builtin_amdgcn_mfma_f32_16x16x32_f16(al1, bh, acc1[ct], 0, 0, 0);
      acc0[ct] = __builtin_amdgcn_mfma_f32_16x16x32_f16(ah0, bl, acc0[ct], 0, 0, 0);
      acc1[ct] = __builtin_amdgcn_mfma_f32_16x16x32_f16(ah1, bl, acc1[ct], 0, 0, 0);
    }
  }

  float bv[11];
#pragma unroll
  for (int ct = 0; ct < 11; ct++) bv[ct] = bias ? bias[ct * 16 + m16] : 0.0f;
#pragma unroll
  for (int r = 0; r < 4; r++) {
    int row0 = rowBase + (quad << 2) + r;
    if (row0 < M) {
      float* op = outp + (size_t)row0 * HC + m16;
#pragma unroll
      for (int ct = 0; ct < 11; ct++) op[ct * 16] = acc0[ct][r] + bv[ct];
    }
    int row1 = row0 + 16;
    if (row1 < M) {
      float* op = outp + (size_t)row1 * HC + m16;
#pragma unroll
      for (int ct = 0; ct < 11; ct++) op[ct * 16] = acc1[ct][r] + bv[ct];
    }
  }
}

// =====================================================================
// GraphNorm: stats (layer 0 only; layers 1-4 fused into attention) +
// finalize -> scale/shift (apply fused into consumers)
// =====================================================================
__global__ void gn_stats_kernel(const float* __restrict__ h, const int* __restrict__ batch,
                                float* __restrict__ stats) {
  int f = threadIdx.x;
  if (f >= HC) return;
  int n0 = blockIdx.x * 64;
  int n1 = min(n0 + 64, N_NODES);
  float s = 0.0f, ss = 0.0f;
  int gcur = batch[n0];
  for (int n = n0; n < n1; n++) {
    int g = batch[n];
    if (g != gcur) {
      atomicAdd(&stats[gcur * HC + f], s);
      atomicAdd(&stats[NGRAPH * HC + gcur * HC + f], ss);
      s = 0.0f; ss = 0.0f; gcur = g;
    }
    float v = h[(size_t)n * HC + f];
    s += v;
    ss += v * v;
  }
  atomicAdd(&stats[gcur * HC + f], s);
  atomicAdd(&stats[NGRAPH * HC + gcur * HC + f], ss);
}

__global__ void gn_finalize_kernel(const float* __restrict__ stats, const int* __restrict__ cntInt,
                                   const float* __restrict__ gnw, const float* __restrict__ gnb,
                                   const float* __restrict__ gnms, int row,
                                   float* __restrict__ scsh) {
  int i = blockIdx.x * 256 + threadIdx.x;
  if (i >= NGRAPH * HC) return;
  int g = i / HC, f = i - g * HC;
  float c = fmaxf((float)cntInt[g], 1.0f);
  float m = stats[i] / c;
  float sq = stats[NGRAPH * HC + i] / c;
  float ms = gnms[row * HC + f];
  float var = sq - m * m * ms * (2.0f - ms);
  float w = gnw[row * HC + f], b = gnb[row * HC + f];
  float scale = w / sqrtf(var + 1e-5f);
  float shift = b - scale * ms * m;
  scsh[i] = scale;
  scsh[NGRAPH * HC + i] = shift;
}

// =====================================================================
// Per-graph node counts via binary search over the SORTED batch array.
// =====================================================================
__global__ void cnt_bsearch_kernel(const int* __restrict__ batch, int* __restrict__ cntInt) {
  int g = threadIdx.x;
  if (g >= NGRAPH) return;
  auto lb = [&](int v) {
    int lo = 0, hi = N_NODES;
    while (lo < hi) {
      int mid = (lo + hi) >> 1;
      if (batch[mid] < v) lo = mid + 1; else hi = mid;
    }
    return lo;
  };
  int a = lb(g), b = lb(g + 1);
  cntInt[g] = b - a;
}

// =====================================================================
// CSR build by destination
// =====================================================================
__global__ void deg_hist_kernel(const int* __restrict__ dstE, int* __restrict__ deg) {
  int e = blockIdx.x * 256 + threadIdx.x;
  if (e < N_EDGES) atomicAdd(&deg[dstE[e]], 1);
}

__global__ void scan1_kernel(const int* __restrict__ deg, int* __restrict__ bsum) {
  __shared__ int sd[256];
  int i = blockIdx.x * 256 + threadIdx.x;
  sd[threadIdx.x] = (i < N_NODES) ? deg[i] : 0;
  __syncthreads();
  for (int s = 128; s > 0; s >>= 1) {
    if (threadIdx.x < s) sd[threadIdx.x] += sd[threadIdx.x + s];
    __syncthreads();
  }
  if (threadIdx.x == 0) bsum[blockIdx.x] = sd[0];
}

__global__ void scan2_kernel(int* __restrict__ bsum, int nb) {
  __shared__ int sd[256];
  int t = threadIdx.x;
  int v0 = (t < nb) ? bsum[t] : 0;
  sd[t] = v0;
  __syncthreads();
  for (int s = 1; s < 256; s <<= 1) {
    int v = (t >= s) ? sd[t - s] : 0;
    __syncthreads();
    sd[t] += v;
    __syncthreads();
  }
  if (t < nb) bsum[t] = sd[t] - v0;  // exclusive
}

__global__ void scan3_kernel(const int* __restrict__ deg, const int* __restrict__ bsum,
                             int* __restrict__ rowptr) {
  __shared__ int sd[256];
  int i = blockIdx.x * 256 + threadIdx.x;
  int t = threadIdx.x;
  int d = (i < N_NODES) ? deg[i] : 0;
  sd[t] = d;
  __syncthreads();
  for (int s = 1; s < 256; s <<= 1) {
    int v = (t >= s) ? sd[t - s] : 0;
    __syncthreads();
    sd[t] += v;
    __syncthreads();
  }
  if (i < N_NODES) rowptr[i] = bsum[blockIdx.x] + sd[t] - d;
  if (i == 0) rowptr[N_NODES] = N_EDGES;
}

__global__ void scatter_kernel(const int* __restrict__ srcE, const int* __restrict__ dstE,
                               const int* __restrict__ rowptr, int* __restrict__ fill,
                               int* __restrict__ colA) {
  int e = blockIdx.x * 256 + threadIdx.x;
  if (e < N_EDGES) {
    int d = dstE[e];
    int pos = rowptr[d] + atomicAdd(&fill[d], 1);
    colA[pos] = srcE[e];
  }
}

// =====================================================================
// GATv2 attention (R9 proven form: wg=256, 4 nodes/block, 2-wide loop)
// + FUSED GraphNorm stats: block parks its 4 nodes' outputs in LDS and
// accumulates per-graph (sum, sumsq) with ~2 atomics per feature per
// block (~195-deep chains per address -> ~1 us total serialization).
// Removes the 35 MB gn_stats re-read per layer.
// =====================================================================
#define AEDGE(V, D, ACC)                                                      \
  do {                                                                        \
    float e0 = (V).x + xrv.x; e0 = fmaxf(e0, 0.2f * e0);                      \
    float e1 = (V).y + xrv.y; e1 = fmaxf(e1, 0.2f * e1);                      \
    float e2 = (V).z + xrv.z; e2 = fmaxf(e2, 0.2f * e2);                      \
    float e3 = (V).w + xrv.w; e3 = fmaxf(e3, 0.2f * e3);                      \
    float p = fmaf(e3, av.w, fmaf(e2, av.z, fmaf(e1, av.y, e0 * av.x)));      \
    p += __shfl_xor(p, 1);                                                    \
    p += __shfl_xor(p, 2);                                                    \
    float pp = __expf(p);                                                     \
    (D) += pp;                                                                \
    (ACC).x = fmaf(pp, (V).x, (ACC).x);                                       \
    (ACC).y = fmaf(pp, (V).y, (ACC).y);                                       \
    (ACC).z = fmaf(pp, (V).z, (ACC).z);                                       \
    (ACC).w = fmaf(pp, (V).w, (ACC).w);                                       \
  } while (0)

__global__ __launch_bounds__(256) void attn_concat_kernel(
    const float* __restrict__ xl, const float* __restrict__ xr,
    const float* __restrict__ att, const int* __restrict__ rowptr,
    const int* __restrict__ colA, float* __restrict__ out,
    const int* __restrict__ batch, float* __restrict__ stats) {
  __shared__ float sv[4 * HC];
  int t = threadIdx.x;
  int node = blockIdx.x * 4 + (t >> 6);
  int lane = t & 63;
  if (lane < 44 && node < N_NODES) {
    const float4 av = *(const float4*)(att + lane * 4);
    size_t base = (size_t)node * HC + lane * 4;
    const float4 xrv = *(const float4*)(xr + base);
    int start = rowptr[node], end = rowptr[node + 1];
    float d = 0.0f, dB = 0.0f;
    float4 acc = make_float4(0.f, 0.f, 0.f, 0.f);
    float4 accB = make_float4(0.f, 0.f, 0.f, 0.f);
    float4 p1, p2;
    if (start < end)     p1 = *(const float4*)(xl + (size_t)colA[start] * HC + lane * 4);
    if (start + 1 < end) p2 = *(const float4*)(xl + (size_t)colA[start + 1] * HC + lane * 4);
    {
      float4 svv = *(const float4*)(xl + base);  // self-loop
      AEDGE(svv, d, acc);
    }
    int j = start;
    for (; j + 3 < end; j += 2) {
      float4 n1 = *(const float4*)(xl + (size_t)colA[j + 2] * HC + lane * 4);
      float4 n2 = *(const float4*)(xl + (size_t)colA[j + 3] * HC + lane * 4);
      AEDGE(p1, d, acc);
      AEDGE(p2, dB, accB);
      p1 = n1; p2 = n2;
    }
    if (j < end)     AEDGE(p1, d, acc);
    if (j + 1 < end) AEDGE(p2, dB, accB);
    if (j + 2 < end) {
      float4 n1 = *(const float4*)(xl + (size_t)colA[j + 2] * HC + lane * 4);
      AEDGE(n1, d, acc);
    }
    d += dB;
    acc.x += accB.x; acc.y += accB.y; acc.z += accB.z; acc.w += accB.w;
    float rd = 1.0f / (d + 1e-16f);
    float4 o = *(const float4*)(out + base);  // residual+bias already there
    o.x = fmaf(acc.x, rd, o.x);
    o.y = fmaf(acc.y, rd, o.y);
    o.z = fmaf(acc.z, rd, o.z);
    o.w = fmaf(acc.w, rd, o.w);
    *(float4*)(out + base) = o;
    *(float4*)(&sv[(t >> 6) * HC + lane * 4]) = o;
  }
  __syncthreads();
  // block-level GraphNorm stats: threads 0..175 fold 4 nodes
  if (t < HC) {
    int gcur = -1;
    float s = 0.0f, ss = 0.0f;
    for (int w = 0; w < 4; w++) {
      int nd = blockIdx.x * 4 + w;
      if (nd >= N_NODES) break;
      int g = batch[nd];
      if (g != gcur) {
        if (gcur >= 0) {
          atomicAdd(&stats[gcur * HC + t], s);
          atomicAdd(&stats[NGRAPH * HC + gcur * HC + t], ss);
        }
        gcur = g; s = 0.0f; ss = 0.0f;
      }
      float v = sv[w * HC + t];
      s += v;
      ss += v * v;
    }
    if (gcur >= 0) {
      atomicAdd(&stats[gcur * HC + t], s);
      atomicAdd(&stats[NGRAPH * HC + gcur * HC + t], ss);
    }
  }
}

__global__ __launch_bounds__(256) void attn_mean_kernel(
    const float* __restrict__ xl, const float* __restrict__ xr,
    const float* __restrict__ att, const int* __restrict__ rowptr,
    const int* __restrict__ colA, const float* __restrict__ res16,
    float* __restrict__ out16) {
  int t = threadIdx.x;
  int node = blockIdx.x * 4 + (t >> 6);
  int lane = t & 63;
  if (node >= N_NODES) return;
  int L = (lane < 44) ? lane : 0;  // lanes 44..63 ride along (zeroed later)
  const float4 av = *(const float4*)(att + L * 4);
  size_t base = (size_t)node * HC + L * 4;
  const float4 xrv = *(const float4*)(xr + base);
  int start = rowptr[node], end = rowptr[node + 1];
  float d = 0.0f, dB = 0.0f;
  float4 acc = make_float4(0.f, 0.f, 0.f, 0.f);
  float4 accB = make_float4(0.f, 0.f, 0.f, 0.f);
  float4 p1, p2;
  if (start < end)     p1 = *(const float4*)(xl + (size_t)colA[start] * HC + L * 4);
  if (start + 1 < end) p2 = *(const float4*)(xl + (size_t)colA[start + 1] * HC + L * 4);
  {
    float4 sv = *(const float4*)(xl + base);
    AEDGE(sv, d, acc);
  }
  int j = start;
  for (; j + 3 < end; j += 2) {
    float4 n1 = *(const float4*)(xl + (size_t)colA[j + 2] * HC + L * 4);
    float4 n2 = *(const float4*)(xl + (size_t)colA[j + 3] * HC + L * 4);
    AEDGE(p1, d, acc);
    AEDGE(p2, dB, accB);
    p1 = n1; p2 = n2;
  }
  if (j < end)     AEDGE(p1, d, acc);
  if (j + 1 < end) AEDGE(p2, dB, accB);
  if (j + 2 < end) {
    float4 n1 = *(const float4*)(xl + (size_t)colA[j + 2] * HC + L * 4);
    AEDGE(n1, d, acc);
  }
  d += dB;
  acc.x += accB.x; acc.y += accB.y; acc.z += accB.z; acc.w += accB.w;
  float rd = 1.0f / (d + 1e-16f);
  float4 o;
  o.x = (lane < 44) ? acc.x * rd : 0.0f;
  o.y = (lane < 44) ? acc.y * rd : 0.0f;
  o.z = (lane < 44) ? acc.z * rd : 0.0f;
  o.w = (lane < 44) ? acc.w * rd : 0.0f;
#pragma unroll
  for (int w = 4; w <= 32; w <<= 1) {
    o.x += __shfl_xor(o.x, w);
    o.y += __shfl_xor(o.y, w);
    o.z += __shfl_xor(o.z, w);
    o.w += __shfl_xor(o.w, w);
  }
  if (lane < 4) {
    const float* rp = res16 + (size_t)node * 16 + lane * 4;
    float4 r = *(const float4*)rp;
    float4 ov;
    ov.x = fmaxf(fmaf(o.x, 1.0f / 11.0f, r.x), 0.0f);
    ov.y = fmaxf(fmaf(o.y, 1.0f / 11.0f, r.y), 0.0f);
    ov.z = fmaxf(fmaf(o.z, 1.0f / 11.0f, r.z), 0.0f);
    ov.w = fmaxf(fmaf(o.w, 1.0f / 11.0f, r.w), 0.0f);
    *(float4*)(out16 + (size_t)node * 16 + lane * 4) = ov;
  }
}

// =====================================================================
// res16 = normApply(h) @ c5_Wres(176x16) + c5_b   (norm+relu fused in load)
// =====================================================================
__global__ __launch_bounds__(256) void res16_kernel(const float* __restrict__ h,
                                                    const float* __restrict__ scsh,
                                                    const int* __restrict__ batch,
                                                    const float* __restrict__ Wres,
                                                    const float* __restrict__ b16,
                                                    float* __restrict__ res16) {
  __shared__ float Ws[176 * 16];
  __shared__ float hs[16 * 176];
  int t = threadIdx.x;
  for (int i = t; i < 176 * 16; i += 256) Ws[i] = Wres[i];
  int n0 = blockIdx.x * 16;
  for (int i = t; i < 16 * 176; i += 256) {
    int row = i / 176, k = i - row * 176;
    int g = batch[n0 + row];
    float v = h[(size_t)n0 * HC + i];
    hs[i] = fmaxf(fmaf(v, scsh[g * HC + k], scsh[(NGRAPH + g) * HC + k]), 0.0f);
  }
  __syncthreads();
  int tx = t & 15, ty = t >> 4;
  float acc = b16[tx];
  for (int k = 0; k < HC; k++) acc = fmaf(hs[ty * HC + k], Ws[k * 16 + tx], acc);
  res16[(size_t)(n0 + ty) * 16 + tx] = acc;
}

// =====================================================================
// Head MLP
// =====================================================================
__global__ __launch_bounds__(256) void head_kernel(
    const float* __restrict__ in16, const float* __restrict__ Wo1,
    const float* __restrict__ bo1, const float* __restrict__ Wo2,
    const float* __restrict__ bo2, const float* __restrict__ Wc,
    const float* __restrict__ bc, float* __restrict__ outp) {
  __shared__ float w1[256], w2[512], wcS[320], b1[16], b2[32], bcS[10];
  int t = threadIdx.x;
  for (int i = t; i < 256; i += 256) w1[i] = Wo1[i];
  for (int i = t; i < 512; i += 256) w2[i] = Wo2[i];
  for (int i = t; i < 320; i += 256) wcS[i] = Wc[i];
  if (t < 16) b1[t] = bo1[t];
  if (t < 32) b2[t] = bo2[t];
  if (t < 10) bcS[t] = bc[t];
  __syncthreads();
  int n = blockIdx.x * 256 + t;
  if (n >= N_NODES) return;
  float x[16];
#pragma unroll
  for (int i = 0; i < 16; i++) x[i] = in16[(size_t)n * 16 + i];
  float o1[16];
#pragma unroll
  for (int j = 0; j < 16; j++) {
    float a = b1[j];
#pragma unroll
    for (int k = 0; k < 16; k++) a = fmaf(x[k], w1[k * 16 + j], a);
    o1[j] = fmaxf(a, 0.0f);
  }
  float o2[32];
#pragma unroll
  for (int j = 0; j < 32; j++) {
    float a = b2[j];
#pragma unroll
    for (int k = 0; k < 16; k++) a = fmaf(o1[k], w2[k * 32 + j], a);
    o2[j] = fmaxf(a, 0.0f);
  }
#pragma unroll
  for (int j = 0; j < 10; j++) {
    float a = bcS[j];
#pragma unroll
    for (int k = 0; k < 32; k++) a = fmaf(o2[k], wcS[k * 10 + j], a);
    outp[(size_t)n * 10 + j] = a;
  }
}

// =====================================================================
extern "C" void kernel_launch(void* const* d_in, const int* in_sizes, int n_in,
                              void* d_out, int out_size, void* d_ws, size_t ws_size,
                              hipStream_t stream) {
  (void)in_sizes; (void)n_in; (void)out_size; (void)ws_size;
  const float* x     = (const float*)d_in[0];
  const int*   ei    = (const int*)d_in[1];
  const int*   srcE  = ei;
  const int*   dstE  = ei + N_EDGES;
  const int*   batch = (const int*)d_in[2];
  const float* W_pre = (const float*)d_in[3];
  const float* b_pre = (const float*)d_in[4];
  const float* gn_w  = (const float*)d_in[5];
  const float* gn_b  = (const float*)d_in[6];
  const float* gn_ms = (const float*)d_in[7];
  const float* cWl   = (const float*)d_in[8];
  const float* cWr   = (const float*)d_in[9];
  const float* cAtt  = (const float*)d_in[10];
  const float* cB    = (const float*)d_in[11];
  const float* cWres = (const float*)d_in[12];
  const float* c5Wl  = (const float*)d_in[13];
  const float* c5Wr  = (const float*)d_in[14];
  const float* c5Att = (const float*)d_in[15];
  const float* c5b   = (const float*)d_in[16];
  const float* c5Wres= (const float*)d_in[17];
  const float* Wo1   = (const float*)d_in[18];
  const float* bo1   = (const float*)d_in[19];
  const float* Wo2   = (const float*)d_in[20];
  const float* bo2   = (const float*)d_in[21];
  const float* Wc    = (const float*)d_in[22];
  const float* bc    = (const float*)d_in[23];

  const size_t FB = (size_t)N_NODES * HC;
  const size_t STB = (size_t)2 * NGRAPH * HC;  // one stats buffer (22528 floats)
  float* ws    = (float*)d_ws;
  float* buf0  = ws;
  float* buf1  = ws + FB;
  float* buf2  = ws + 2 * FB;
  float* buf3  = ws + 3 * FB;
  float* res16 = ws + 4 * FB;
  float* out16 = res16 + (size_t)N_NODES * 16;
  float* stats = out16 + (size_t)N_NODES * 16;         // 5 buffers
  float* scsh  = stats + 5 * STB;
  _Float16* wph = (_Float16*)(scsh + STB);             // 991232 halves
  int* ibase   = (int*)((char*)wph + (size_t)991232 * 2);
  int* cntInt  = ibase;
  int* deg     = ibase + 64;
  int* fill    = deg + N_NODES;
  int* rowptr  = fill + N_NODES;
  int* colA    = rowptr + N_NODES + 1;
  int* bsum    = colA + N_EDGES;

  const int NB = (N_NODES + 255) / 256;

  hipMemsetAsync(deg, 0, sizeof(int) * 2 * N_NODES, stream);
  hipMemsetAsync(stats, 0, sizeof(float) * 5 * STB, stream);  // all layers at once

  prep_kernel<<<(TOT_PAIRS + 255) / 256, 256, 0, stream>>>(W_pre, cWl, cWr, cWres, c5Wl, c5Wr, wph);
  cnt_bsearch_kernel<<<1, 64, 0, stream>>>(batch, cntInt);
  deg_hist_kernel<<<(N_EDGES + 255) / 256, 256, 0, stream>>>(dstE, deg);
  scan1_kernel<<<NB, 256, 0, stream>>>(deg, bsum);
  scan2_kernel<<<1, 256, 0, stream>>>(bsum, NB);
  scan3_kernel<<<NB, 256, 0, stream>>>(deg, bsum, rowptr);
  scatter_kernel<<<(N_EDGES + 255) / 256, 256, 0, stream>>>(srcE, dstE, rowptr, fill, colA);

  // pre: buf0 = x @ W_pre + b_pre  (raw, no norm on input)
  gemm_mfma<<<GX8 * 1 * 8, 256, 0, stream>>>(x, N_NODES, IN_F, 4, 1, wph, 0,
                                             nullptr, nullptr,
                                             b_pre, nullptr, nullptr,
                                             buf0, nullptr, nullptr);
  gn_stats_kernel<<<(N_NODES + 63) / 64, 256, 0, stream>>>(buf0, batch, stats);
  gn_finalize_kernel<<<(NGRAPH * HC + 255) / 256, 256, 0, stream>>>(stats, cntInt, gn_w, gn_b, gn_ms, 0, scsh);

  float* h = buf0;  // raw buffer; norm applied on the fly by consumers
  float* o = buf3;
  for (int i = 0; i < 4; i++) {
    const _Float16* Wcat_i = wph + PREH + (size_t)(3 * i) * MATH;
    gemm_mfma<<<GX8 * 3 * 8, 256, 0, stream>>>(h, N_NODES, HC, 6, 3, Wcat_i, MATH,
                                               scsh, batch,
                                               nullptr, nullptr, cB + i * HC,
                                               buf1, buf2, o);
    float* st = stats + (size_t)(i + 1) * STB;
    attn_concat_kernel<<<(N_NODES + 3) / 4, 256, 0, stream>>>(buf1, buf2, cAtt + i * HC,
                                                              rowptr, colA, o, batch, st);
    gn_finalize_kernel<<<(NGRAPH * HC + 255) / 256, 256, 0, stream>>>(st, cntInt, gn_w, gn_b, gn_ms, i + 1, scsh);
    float* tmp = h; h = o; o = tmp;
  }

  // conv5 (input = raw h with scsh row 4 fused in consumers)
  const _Float16* Wc5 = wph + PREH + (size_t)12 * MATH;
  gemm_mfma<<<GX8 * 2 * 8, 256, 0, stream>>>(h, N_NODES, HC, 6, 2, Wc5, MATH,
                                             scsh, batch,
                                             nullptr, nullptr, nullptr,
                                             buf1, buf2, nullptr);
  res16_kernel<<<N_NODES / 16, 256, 0, stream>>>(h, scsh, batch, c5Wres, c5b, res16);
  attn_mean_kernel<<<(N_NODES + 3) / 4, 256, 0, stream>>>(buf1, buf2, c5Att, rowptr, colA, res16, out16);

  head_kernel<<<NB, 256, 0, stream>>>(out16, Wo1, bo1, Wo2, bo2, Wc, bc, (float*)d_out);
}